// Round 5
// baseline (536.959 us; speedup 1.0000x reference)
//
#include <hip/hip_runtime.h>

typedef unsigned short u16;
typedef unsigned int u32;
typedef _Float16 f16;
typedef f16 f16x2 __attribute__((ext_vector_type(2)));
typedef f16 f16x8 __attribute__((ext_vector_type(8)));
typedef __fp16 h16x2 __attribute__((ext_vector_type(2)));  // pkrtz return type
typedef float f32x4 __attribute__((ext_vector_type(4)));

#define M_DIM 8192
#define N_DIM 4096
#define K_DIM 4096

// ---------------------------------------------------------------------------
// Fused pre-pass.
//  range 0: X fp32 -> fp16 (coalesced: 1 float4 load + 1 uint2 store, x2)
//  range 1: FULL dequant of W to fp16 [4096][4096] (replaces W4+IM ranges).
//           Bit-identical arithmetic to the old in-loop splice path:
//           w = fma_f16( f16(16+v), f16(1/sc), f16(mn - 16*f16(1/sc)) )
//           (splice produced exactly fp16(16+v); fma identical) -> the GEMM
//           output is bit-identical to the verified r0 kernel.
// ---------------------------------------------------------------------------
#define XCVT_BLOCKS 16384  // M*K/8/256
#define BH_BLOCKS 8192     // N*K/8/256

__global__ __launch_bounds__(256) void prep_kernel(
    const float4* __restrict__ x, uint2* __restrict__ xh,
    const int* __restrict__ packed, const float* __restrict__ mn,
    const float* __restrict__ scale, uint4* __restrict__ bh) {
  int b = blockIdx.x;
  if (b < XCVT_BLOCKS) {
    int i0 = b * 512 + threadIdx.x;  // float4 index == uint2 index
    float4 a0 = x[i0];
    float4 a1 = x[i0 + 256];
    h16x2 h0 = __builtin_amdgcn_cvt_pkrtz(a0.x, a0.y);
    h16x2 h1 = __builtin_amdgcn_cvt_pkrtz(a0.z, a0.w);
    h16x2 h2 = __builtin_amdgcn_cvt_pkrtz(a1.x, a1.y);
    h16x2 h3 = __builtin_amdgcn_cvt_pkrtz(a1.z, a1.w);
    uint2 o0, o1;
    o0.x = __builtin_bit_cast(u32, h0);
    o0.y = __builtin_bit_cast(u32, h1);
    o1.x = __builtin_bit_cast(u32, h2);
    o1.y = __builtin_bit_cast(u32, h3);
    xh[i0] = o0;
    xh[i0 + 256] = o1;
  } else {
    // W dequant: thread -> (n, w) = 8 consecutive k of row n, k0 = w*8.
    // pos = (w&7)*8 + t (all in same 32-half since 8|32): nibble =
    // (packed[n][g][(w&3)*8 + t] >> ((w&7)<4 ? 4:0)) & 0xF.
    int idx = (b - XCVT_BLOCKS) * 256 + threadIdx.x;  // n*512 + w
    int n = idx >> 9, w = idx & 511;
    int g = w >> 3;
    int sh = ((w & 7) < 4) ? 4 : 0;
    const int* p = packed + n * 2048 + g * 32 + (w & 3) * 8;
    float sc = scale[n * 64 + g];
    float m = mn[n * 64 + g];
    f16 invh = (f16)(1.0f / sc);
    f16 mnh = (f16)(m - 16.0f * (float)invh);
    f16x2 inv2, mn2;
    inv2[0] = invh;
    inv2[1] = invh;
    mn2[0] = mnh;
    mn2[1] = mnh;
    union {
      f16x8 v;
      uint4 d;
    } o;
#pragma unroll
    for (int u = 0; u < 4; u++) {
      u32 v0 = ((u32)p[2 * u] >> sh) & 0xFu;
      u32 v1 = ((u32)p[2 * u + 1] >> sh) & 0xFu;
      f16x2 q;
      q[0] = (f16)(int)(16 + v0);  // == splice's fp16(16+v), exact
      q[1] = (f16)(int)(16 + v1);
      f16x2 wv = __builtin_elementwise_fma(q, inv2, mn2);
      o.v[2 * u] = wv[0];
      o.v[2 * u + 1] = wv[1];
    }
    bh[idx] = o.d;  // Bh[n][w*8 .. +8] fp16, 16B coalesced
  }
}

// ---------------------------------------------------------------------------
// GEMM: C[M][N] = Xh[M][K](fp16) * Bh[N][K](fp16)^T + bias
// Faithful m201 8-phase port (T3+T4+T2+T5), B pre-dequantized so phases are
// MFMA-pure:
//  * 256x256 tile, 512 thr = 8 waves (2M x 4N), wave tile 128x64, acc[8][4].
//  * LDS: 4 K-half slots (h = 2t+s, slot h&3): AS/BS [256 rows][32 k] fp16,
//    16KB each -> 128 KB total. Prefetch distance 3 halves.
//  * 2 phases per half, each: {4-8 ds_read_b128; 2 global_load_lds (one
//    A+B chunk of half h+3); [vmcnt(8) at half end]; s_barrier; lgkmcnt(0)+
//    sched_barrier(0); setprio(1); 16 MFMA; setprio(0); s_barrier}.
//    af[0..3]+bf[0..3] read in P_a, af[4..7] in P_b, bf REUSED (no dup).
//  * Counted vmcnt: in-loop VMEM is ONLY the 4 gloads/half. At half-h end,
//    outstanding = halves {h+2, h+3} = 8 -> vmcnt(8) waits exactly for h+1.
//    Tail: h==125 -> vmcnt(4), h==126 -> vmcnt(0).
//  * Chunk-swizzle both A and B (verified r1/r4 pair): store-side via
//    pre-swizzled global source chunk cs = cd ^ (row bits[2:1]); read chunk
//    lq ^ ((lr>>1)&3) -> 2 lanes/bank-slot = free.
//  * XCD-chunked bijective block swizzle (512 % 8 == 0).
//  * MFMA shape/order/epilogue identical to verified r0 -> identical bits.
// ---------------------------------------------------------------------------
__device__ __forceinline__ void gload_lds16(const void* g, void* l) {
  __builtin_amdgcn_global_load_lds(
      (const __attribute__((address_space(1))) void*)g,
      (__attribute__((address_space(3))) void*)l, 16, 0, 0);
}

__global__ __launch_bounds__(512, 2) void gemm4_kernel(
    const u16* __restrict__ A,   // fp16 [8192][4096]
    const u16* __restrict__ Bh,  // fp16 [4096][4096] dequantized W
    const float* __restrict__ bias, float* __restrict__ C) {
  __shared__ alignas(16) u16 AS[4][256 * 32];  // 4 x 16 KB, chunk-swizzled
  __shared__ alignas(16) u16 BS[4][256 * 32];  // 4 x 16 KB, chunk-swizzled

  const int tid = threadIdx.x;
  const int wave = tid >> 6, lane = tid & 63;
  const int lr = lane & 15, lq = lane >> 4;
  const int wg = ((int)blockIdx.x & 7) * 64 + ((int)blockIdx.x >> 3);
  const int bn = wg & 15, bm = wg >> 4;
  const int m0 = bm << 8, n0 = bn << 8;
  const int wm = (wave & 1) << 7, wn = (wave >> 1) << 6;

  // ---- staging bases: per half, wave w writes rows w*32..+31 in 2 calls ----
  // call u: dest = slot + w*2048 + u*1024 + lane*16 (linear, lane x 16B);
  // that lands (row = w*32 + u*16 + (lane>>2), chunk cd = lane&3); source
  // chunk cs = cd ^ ((row>>1)&3) = (lane&3) ^ ((lane>>3)&3)  [w*32, u*16
  // preserve row bits 2:1].
  const int csA = ((lane & 3) ^ ((lane >> 3) & 3)) << 3;  // u16 offset
  const u16* pA0 = A + (size_t)(m0 + (wave << 5) + (lane >> 2)) * K_DIM + csA;
  const u16* pA1 = pA0 + (size_t)16 * K_DIM;
  const u16* pB0 = Bh + (size_t)(n0 + (wave << 5) + (lane >> 2)) * K_DIM + csA;
  const u16* pB1 = pB0 + (size_t)16 * K_DIM;
  char* dA = (char*)(&AS[0][0]) + (wave << 11) + (lane << 4);
  char* dB = (char*)(&BS[0][0]) + (wave << 11) + (lane << 4);

  // ---- read offsets (identical formula family to verified r0/r4) ----
  const int swz = (lq ^ ((lr >> 1) & 3)) << 4;
  const int aoff = (wm + lr) * 64 + swz;
  const int boff = (wn + lr) * 64 + swz;

  // 2 gloads (A+B) for chunk u of half hh -> slot hh&3
#define STAGEU(hh, u)                                                    \
  do {                                                                   \
    gload_lds16(((u) ? pA1 : pA0) + (hh) * 32,                           \
                dA + (((hh) & 3) << 14) + ((u) << 10));                  \
    gload_lds16(((u) ? pB1 : pB0) + (hh) * 32,                           \
                dB + (((hh) & 3) << 14) + ((u) << 10));                  \
  } while (0)

  f32x4 acc[8][4] = {};

  // ---- prologue: stage halves 0,1,2 (12 loads); wait h0 (oldest 4) ----
  STAGEU(0, 0);
  STAGEU(0, 1);
  STAGEU(1, 0);
  STAGEU(1, 1);
  STAGEU(2, 0);
  STAGEU(2, 1);
  asm volatile("s_waitcnt vmcnt(8)" ::: "memory");
  __builtin_amdgcn_s_barrier();

#pragma unroll 1
  for (int h = 0; h < 128; ++h) {  // half-tile h: k = h*32 .. +32
    const char* aS = (const char*)(&AS[0][0]) + ((h & 3) << 14);
    const char* bS = (const char*)(&BS[0][0]) + ((h & 3) << 14);

    // ---- P_a: af[0..3] + bf[0..3]; stage chunk 0 of h+3; 16 MFMA ----
    f16x8 af[4], bf[4];
#pragma unroll
    for (int i = 0; i < 4; i++)
      af[i] = *(const f16x8*)(aS + aoff + i * 1024);
#pragma unroll
    for (int j = 0; j < 4; j++)
      bf[j] = *(const f16x8*)(bS + boff + j * 1024);
    if (h <= 124) STAGEU(h + 3, 0);
    __builtin_amdgcn_s_barrier();
    asm volatile("s_waitcnt lgkmcnt(0)" ::: "memory");
    __builtin_amdgcn_sched_barrier(0);
    __builtin_amdgcn_s_setprio(1);
#pragma unroll
    for (int i = 0; i < 4; i++)
#pragma unroll
      for (int j = 0; j < 4; j++)
        acc[i][j] = __builtin_amdgcn_mfma_f32_16x16x32_f16(af[i], bf[j],
                                                           acc[i][j], 0, 0, 0);
    __builtin_amdgcn_s_setprio(0);
    __builtin_amdgcn_s_barrier();

    // ---- P_b: af[4..7]; stage chunk 1 of h+3; counted vmcnt; 16 MFMA ----
    f16x8 ag[4];
#pragma unroll
    for (int i = 0; i < 4; i++)
      ag[i] = *(const f16x8*)(aS + aoff + (4 + i) * 1024);
    if (h <= 124) STAGEU(h + 3, 1);
    // outstanding after issue: halves {h+2, h+3} = 8 -> vmcnt(8) == h+1 done
    if (h <= 124)
      asm volatile("s_waitcnt vmcnt(8)" ::: "memory");
    else if (h == 125)
      asm volatile("s_waitcnt vmcnt(4)" ::: "memory");
    else if (h == 126)
      asm volatile("s_waitcnt vmcnt(0)" ::: "memory");
    __builtin_amdgcn_s_barrier();
    asm volatile("s_waitcnt lgkmcnt(0)" ::: "memory");
    __builtin_amdgcn_sched_barrier(0);
    __builtin_amdgcn_s_setprio(1);
#pragma unroll
    for (int i = 0; i < 4; i++)
#pragma unroll
      for (int j = 0; j < 4; j++)
        acc[4 + i][j] = __builtin_amdgcn_mfma_f32_16x16x32_f16(
            ag[i], bf[j], acc[4 + i][j], 0, 0, 0);
    __builtin_amdgcn_s_setprio(0);
    __builtin_amdgcn_s_barrier();
  }
#undef STAGEU

  // Epilogue: C/D layout col=lane&15, row=(lane>>4)*4+t (verified r0)
#pragma unroll
  for (int j = 0; j < 4; j++) {
    int n = n0 + wn + j * 16 + lr;
    float bv = bias[n];
#pragma unroll
    for (int i = 0; i < 8; i++) {
      int mb = m0 + wm + i * 16 + (lq << 2);
#pragma unroll
      for (int t = 0; t < 4; t++)
        C[(size_t)(mb + t) * N_DIM + n] = acc[i][j][t] + bv;
    }
  }
}

// ---------------- fallback (only if ws too small): naive tiled fp32 --------
__global__ __launch_bounds__(256) void fallback_gemm(
    const float* __restrict__ x, const int* __restrict__ packed,
    const float* __restrict__ mn, const float* __restrict__ scale,
    const float* __restrict__ bias, float* __restrict__ out) {
  __shared__ float As[16][17];
  __shared__ float Bs[16][17];
  int tx = threadIdx.x & 15, ty = threadIdx.x >> 4;
  int m = blockIdx.y * 16 + ty;
  int n = blockIdx.x * 16 + tx;
  float acc = 0.f;
  for (int k0 = 0; k0 < K_DIM; k0 += 16) {
    As[ty][tx] = x[(size_t)m * K_DIM + k0 + tx];
    int nn = blockIdx.x * 16 + ty;
    int k = k0 + tx;
    int g = k >> 6, pos = k & 63;
    int p = packed[nn * 2048 + g * 32 + (pos & 31)];
    int v = (pos < 32) ? ((p >> 4) & 0xF) : (p & 0xF);
    Bs[ty][tx] = (float)v / scale[nn * 64 + g] + mn[nn * 64 + g];
    __syncthreads();
#pragma unroll
    for (int kk = 0; kk < 16; kk++) acc += As[ty][kk] * Bs[tx][kk];
    __syncthreads();
  }
  out[(size_t)m * N_DIM + n] = acc + bias[n];
}

extern "C" void kernel_launch(void* const* d_in, const int* in_sizes, int n_in,
                              void* d_out, int out_size, void* d_ws,
                              size_t ws_size, hipStream_t stream) {
  const float* x = (const float*)d_in[0];      // [4,2048,4096] fp32
  const int* packed = (const int*)d_in[1];     // [4096,64,32] int32
  const float* mn = (const float*)d_in[2];     // [4096,64,1]
  const float* scale = (const float*)d_in[3];  // [4096,64,1]
  const float* bias = (const float*)d_in[4];   // [4096]
  float* out = (float*)d_out;                  // [8192,4096]

  const size_t offBh = (size_t)M_DIM * K_DIM * 2;          // Xh: 64 MB
  const size_t need = offBh + (size_t)N_DIM * K_DIM * 2;   // Bh: 32 MB

  if (ws_size >= need) {
    u16* Xh = (u16*)d_ws;
    u16* Bhp = (u16*)((char*)d_ws + offBh);
    prep_kernel<<<XCVT_BLOCKS + BH_BLOCKS, 256, 0, stream>>>(
        (const float4*)x, (uint2*)Xh, packed, mn, scale, (uint4*)Bhp);
    gemm4_kernel<<<(M_DIM / 256) * (N_DIM / 256), 512, 0, stream>>>(
        Xh, Bhp, bias, out);
  } else {
    dim3 grid(N_DIM / 16, M_DIM / 16);
    fallback_gemm<<<grid, 256, 0, stream>>>(x, packed, mn, scale, bias, out);
  }
}

// Round 6
// 527.929 us; speedup vs baseline: 1.0171x; 1.0171x over previous
//
#include <hip/hip_runtime.h>

typedef unsigned short u16;
typedef unsigned int u32;
typedef _Float16 f16;
typedef f16 f16x2 __attribute__((ext_vector_type(2)));
typedef f16 f16x8 __attribute__((ext_vector_type(8)));
typedef __fp16 h16x2 __attribute__((ext_vector_type(2)));  // pkrtz return type
typedef float f32x4 __attribute__((ext_vector_type(4)));

#define M_DIM 8192
#define N_DIM 4096
#define K_DIM 4096

// ---------------------------------------------------------------------------
// Fused pre-pass (unchanged from r5).
//  range 0: X fp32 -> fp16 (coalesced)
//  range 1: FULL dequant of W to fp16 [4096][4096]; bit-identical arithmetic
//           to the verified in-loop splice path.
// ---------------------------------------------------------------------------
#define XCVT_BLOCKS 16384  // M*K/8/256
#define BH_BLOCKS 8192     // N*K/8/256

__global__ __launch_bounds__(256) void prep_kernel(
    const float4* __restrict__ x, uint2* __restrict__ xh,
    const int* __restrict__ packed, const float* __restrict__ mn,
    const float* __restrict__ scale, uint4* __restrict__ bh) {
  int b = blockIdx.x;
  if (b < XCVT_BLOCKS) {
    int i0 = b * 512 + threadIdx.x;  // float4 index == uint2 index
    float4 a0 = x[i0];
    float4 a1 = x[i0 + 256];
    h16x2 h0 = __builtin_amdgcn_cvt_pkrtz(a0.x, a0.y);
    h16x2 h1 = __builtin_amdgcn_cvt_pkrtz(a0.z, a0.w);
    h16x2 h2 = __builtin_amdgcn_cvt_pkrtz(a1.x, a1.y);
    h16x2 h3 = __builtin_amdgcn_cvt_pkrtz(a1.z, a1.w);
    uint2 o0, o1;
    o0.x = __builtin_bit_cast(u32, h0);
    o0.y = __builtin_bit_cast(u32, h1);
    o1.x = __builtin_bit_cast(u32, h2);
    o1.y = __builtin_bit_cast(u32, h3);
    xh[i0] = o0;
    xh[i0 + 256] = o1;
  } else {
    int idx = (b - XCVT_BLOCKS) * 256 + threadIdx.x;  // n*512 + w
    int n = idx >> 9, w = idx & 511;
    int g = w >> 3;
    int sh = ((w & 7) < 4) ? 4 : 0;
    const int* p = packed + n * 2048 + g * 32 + (w & 3) * 8;
    float sc = scale[n * 64 + g];
    float m = mn[n * 64 + g];
    f16 invh = (f16)(1.0f / sc);
    f16 mnh = (f16)(m - 16.0f * (float)invh);
    f16x2 inv2, mn2;
    inv2[0] = invh;
    inv2[1] = invh;
    mn2[0] = mnh;
    mn2[1] = mnh;
    union {
      f16x8 v;
      uint4 d;
    } o;
#pragma unroll
    for (int u = 0; u < 4; u++) {
      u32 v0 = ((u32)p[2 * u] >> sh) & 0xFu;
      u32 v1 = ((u32)p[2 * u + 1] >> sh) & 0xFu;
      f16x2 q;
      q[0] = (f16)(int)(16 + v0);  // == splice's fp16(16+v), exact
      q[1] = (f16)(int)(16 + v1);
      f16x2 wv = __builtin_elementwise_fma(q, inv2, mn2);
      o.v[2 * u] = wv[0];
      o.v[2 * u + 1] = wv[1];
    }
    bh[idx] = o.d;
  }
}

// ---------------------------------------------------------------------------
// GEMM: C[M][N] = Xh[M][K](fp16) * Bh[N][K](fp16)^T + bias
// r6 = r5's 8-phase skeleton, UN-PINNED:
//  * sched_barrier(0) and explicit lgkmcnt(0) REMOVED — compiler emits
//    fine-grained lgkmcnt per MFMA and interleaves address math into the
//    cluster (m141: pinning costs; r5 counters: VALU ~490cyc/half serialized).
//  * 4-half unroll: slot bases compile-time -> every ds_read_b128 is
//    base-VGPR + imm-offset (max offset 65520 < 64K, verified); staging uses
//    4 incrementing pointers + small imms. Kills the per-half address VALU.
//  * Unchanged verified pieces: 256x256/8-wave/128x64 geometry; 4-slot LDS
//    (128 KB); counted vmcnt(8) per half (never 0 until tail); setprio(1)
//    around each 16-MFMA cluster; A/B chunk-swizzle (0 conflicts in r5);
//    XCD-chunked bijective block swizzle; epilogue layout.
//  Correctness: WAR on a slot — reads of slot s complete before each wave's
//  MFMAs, which precede the end-of-half barrier; the overwriting gloads are
//  issued after that barrier (LDS ops don't move across s_barrier). RAW —
//  vmcnt(8) + barrier before first read of a staged half (distance 3).
// ---------------------------------------------------------------------------
__device__ __forceinline__ void gload_lds16(const void* g, void* l) {
  __builtin_amdgcn_global_load_lds(
      (const __attribute__((address_space(1))) void*)g,
      (__attribute__((address_space(3))) void*)l, 16, 0, 0);
}

__global__ __launch_bounds__(512, 2) void gemm4_kernel(
    const u16* __restrict__ A,   // fp16 [8192][4096]
    const u16* __restrict__ Bh,  // fp16 [4096][4096] dequantized W
    const float* __restrict__ bias, float* __restrict__ C) {
  __shared__ alignas(16) u16 AS[4][256 * 32];  // 4 x 16 KB, chunk-swizzled
  __shared__ alignas(16) u16 BS[4][256 * 32];  // 4 x 16 KB, chunk-swizzled

  const int tid = threadIdx.x;
  const int wave = tid >> 6, lane = tid & 63;
  const int lr = lane & 15, lq = lane >> 4;
  const int wg = ((int)blockIdx.x & 7) * 64 + ((int)blockIdx.x >> 3);
  const int bn = wg & 15, bm = wg >> 4;
  const int m0 = bm << 8, n0 = bn << 8;
  const int wm = (wave & 1) << 7, wn = (wave >> 1) << 6;

  // ---- staging bases: per half, wave w writes rows w*32..+31 in 2 chunks ----
  // chunk u dest = slot + w*2048 + u*1024 + lane*16 (linear); source chunk
  // pre-swizzled: cs = (lane&3) ^ ((lane>>3)&3)  (= cd ^ row bits[2:1]).
  const int csA = ((lane & 3) ^ ((lane >> 3) & 3)) << 3;  // u16 offset
  const u16* pA0 = A + (size_t)(m0 + (wave << 5) + (lane >> 2)) * K_DIM + csA;
  const u16* pA1 = pA0 + (size_t)16 * K_DIM;
  const u16* pB0 = Bh + (size_t)(n0 + (wave << 5) + (lane >> 2)) * K_DIM + csA;
  const u16* pB1 = pB0 + (size_t)16 * K_DIM;
  char* dA = (char*)(&AS[0][0]) + (wave << 11) + (lane << 4);
  char* dB = (char*)(&BS[0][0]) + (wave << 11) + (lane << 4);

  // ---- read bases (loop-invariant VGPRs; all reads are base + imm) ----
  const int swz = (lq ^ ((lr >> 1) & 3)) << 4;
  const char* aRd = (const char*)(&AS[0][0]) + (wm + lr) * 64 + swz;
  const char* bRd = (const char*)(&BS[0][0]) + (wn + lr) * 64 + swz;

  f32x4 acc[8][4] = {};

  // ---- prologue: stage halves 0,1,2 into slots 0,1,2; wait oldest 4 ----
#pragma unroll
  for (int h = 0; h < 3; h++) {
    gload_lds16(pA0 + h * 32, dA + h * 16384);
    gload_lds16(pB0 + h * 32, dB + h * 16384);
    gload_lds16(pA1 + h * 32, dA + h * 16384 + 1024);
    gload_lds16(pB1 + h * 32, dB + h * 16384 + 1024);
  }
  asm volatile("s_waitcnt vmcnt(8)" ::: "memory");
  __builtin_amdgcn_s_barrier();

  // staging pointers lead the compute by 3 halves
  const u16* pAs0 = pA0 + 3 * 32;
  const u16* pAs1 = pA1 + 3 * 32;
  const u16* pBs0 = pB0 + 3 * 32;
  const u16* pBs1 = pB1 + 3 * 32;

  // One 32-k half: slot sl_ (compile-time), optional stage of half+3 into
  // slot (sl_+3)&3, counted vmcnt wc_ at end. No lgkmcnt(0)/sched_barrier —
  // compiler inserts fine-grained waits and interleaves freely.
#define HALF(hr_, sl_, dostage_, wc_)                                        \
  do {                                                                       \
    f16x8 af[4], bf[4];                                                      \
    _Pragma("unroll") for (int i = 0; i < 4; i++) af[i] =                    \
        *(const f16x8*)(aRd + (sl_)*16384 + i * 1024);                       \
    _Pragma("unroll") for (int j = 0; j < 4; j++) bf[j] =                    \
        *(const f16x8*)(bRd + (sl_)*16384 + j * 1024);                       \
    if (dostage_) {                                                          \
      gload_lds16(pAs0 + (hr_)*32, dA + (((sl_) + 3) & 3) * 16384);          \
      gload_lds16(pBs0 + (hr_)*32, dB + (((sl_) + 3) & 3) * 16384);          \
    }                                                                        \
    __builtin_amdgcn_s_barrier();                                            \
    __builtin_amdgcn_s_setprio(1);                                           \
    _Pragma("unroll") for (int i = 0; i < 4; i++)                            \
        _Pragma("unroll") for (int j = 0; j < 4; j++) acc[i][j] =            \
        __builtin_amdgcn_mfma_f32_16x16x32_f16(af[i], bf[j], acc[i][j], 0,   \
                                               0, 0);                        \
    __builtin_amdgcn_s_setprio(0);                                           \
    __builtin_amdgcn_s_barrier();                                            \
    f16x8 ag[4];                                                             \
    _Pragma("unroll") for (int i = 0; i < 4; i++) ag[i] =                    \
        *(const f16x8*)(aRd + (sl_)*16384 + (4 + i) * 1024);                 \
    if (dostage_) {                                                          \
      gload_lds16(pAs1 + (hr_)*32, dA + (((sl_) + 3) & 3) * 16384 + 1024);   \
      gload_lds16(pBs1 + (hr_)*32, dB + (((sl_) + 3) & 3) * 16384 + 1024);   \
    }                                                                        \
    if ((wc_) == 8)                                                          \
      asm volatile("s_waitcnt vmcnt(8)" ::: "memory");                       \
    else if ((wc_) == 4)                                                     \
      asm volatile("s_waitcnt vmcnt(4)" ::: "memory");                       \
    else if ((wc_) == 0)                                                     \
      asm volatile("s_waitcnt vmcnt(0)" ::: "memory");                       \
    __builtin_amdgcn_s_barrier();                                            \
    __builtin_amdgcn_s_setprio(1);                                           \
    _Pragma("unroll") for (int i = 0; i < 4; i++)                            \
        _Pragma("unroll") for (int j = 0; j < 4; j++) acc[4 + i][j] =        \
        __builtin_amdgcn_mfma_f32_16x16x32_f16(ag[i], bf[j], acc[4 + i][j],  \
                                               0, 0, 0);                     \
    __builtin_amdgcn_s_setprio(0);                                           \
    __builtin_amdgcn_s_barrier();                                            \
  } while (0)

#pragma unroll 1
  for (int t = 0; t < 31; ++t) {  // halves 4t .. 4t+3; stage 4t+3 .. 4t+6
    HALF(0, 0, 1, 8);
    HALF(1, 1, 1, 8);
    HALF(2, 2, 1, 8);
    HALF(3, 3, 1, 8);
    pAs0 += 128;
    pAs1 += 128;
    pBs0 += 128;
    pBs1 += 128;
  }
  // tail: halves 124..127 (h=124 stages 127; then drain 8 -> 4 -> 0)
  HALF(0, 0, 1, 8);
  HALF(1, 1, 0, 4);
  HALF(2, 2, 0, 0);
  HALF(3, 3, 0, -1);
#undef HALF

  // Epilogue: C/D layout col=lane&15, row=(lane>>4)*4+t (verified r0)
#pragma unroll
  for (int j = 0; j < 4; j++) {
    int n = n0 + wn + j * 16 + lr;
    float bv = bias[n];
#pragma unroll
    for (int i = 0; i < 8; i++) {
      int mb = m0 + wm + i * 16 + (lq << 2);
#pragma unroll
      for (int t = 0; t < 4; t++)
        C[(size_t)(mb + t) * N_DIM + n] = acc[i][j][t] + bv;
    }
  }
}

// ---------------- fallback (only if ws too small): naive tiled fp32 --------
__global__ __launch_bounds__(256) void fallback_gemm(
    const float* __restrict__ x, const int* __restrict__ packed,
    const float* __restrict__ mn, const float* __restrict__ scale,
    const float* __restrict__ bias, float* __restrict__ out) {
  __shared__ float As[16][17];
  __shared__ float Bs[16][17];
  int tx = threadIdx.x & 15, ty = threadIdx.x >> 4;
  int m = blockIdx.y * 16 + ty;
  int n = blockIdx.x * 16 + tx;
  float acc = 0.f;
  for (int k0 = 0; k0 < K_DIM; k0 += 16) {
    As[ty][tx] = x[(size_t)m * K_DIM + k0 + tx];
    int nn = blockIdx.x * 16 + ty;
    int k = k0 + tx;
    int g = k >> 6, pos = k & 63;
    int p = packed[nn * 2048 + g * 32 + (pos & 31)];
    int v = (pos < 32) ? ((p >> 4) & 0xF) : (p & 0xF);
    Bs[ty][tx] = (float)v / scale[nn * 64 + g] + mn[nn * 64 + g];
    __syncthreads();
#pragma unroll
    for (int kk = 0; kk < 16; kk++) acc += As[ty][kk] * Bs[tx][kk];
    __syncthreads();
  }
  out[(size_t)m * N_DIM + n] = acc + bias[n];
}

extern "C" void kernel_launch(void* const* d_in, const int* in_sizes, int n_in,
                              void* d_out, int out_size, void* d_ws,
                              size_t ws_size, hipStream_t stream) {
  const float* x = (const float*)d_in[0];      // [4,2048,4096] fp32
  const int* packed = (const int*)d_in[1];     // [4096,64,32] int32
  const float* mn = (const float*)d_in[2];     // [4096,64,1]
  const float* scale = (const float*)d_in[3];  // [4096,64,1]
  const float* bias = (const float*)d_in[4];   // [4096]
  float* out = (float*)d_out;                  // [8192,4096]

  const size_t offBh = (size_t)M_DIM * K_DIM * 2;          // Xh: 64 MB
  const size_t need = offBh + (size_t)N_DIM * K_DIM * 2;   // Bh: 32 MB

  if (ws_size >= need) {
    u16* Xh = (u16*)d_ws;
    u16* Bhp = (u16*)((char*)d_ws + offBh);
    prep_kernel<<<XCVT_BLOCKS + BH_BLOCKS, 256, 0, stream>>>(
        (const float4*)x, (uint2*)Xh, packed, mn, scale, (uint4*)Bhp);
    gemm4_kernel<<<(M_DIM / 256) * (N_DIM / 256), 512, 0, stream>>>(
        Xh, Bhp, bias, out);
  } else {
    dim3 grid(N_DIM / 16, M_DIM / 16);
    fallback_gemm<<<grid, 256, 0, stream>>>(x, packed, mn, scale, bias, out);
  }
}